// Round 11
// baseline (638.900 us; speedup 1.0000x reference)
//
#include <hip/hip_runtime.h>
#include <hip/hip_bf16.h>
#include <math.h>

// Problem constants (from reference)
#define N_NODES 50000
#define N_EDGES 800000
#define NEG     0.2f

// Workspace layout (in 4-byte words)
#define OFF_CNT    0          // cnt: N ints (in-degree, real edges only)
#define OFF_ROWPTR 50000      // row_ptr: N ints
#define OFF_CURSOR 100000     // cursor: N ints
#define OFF_PART   150000     // scan partials: 256 ints
#define OFF_CSRSE  150256     // csr_se: E int2 + 16 int2 pad = 1,600,032 words
#define OFF_XL     1750288    // xl: N*128 floats
#define OFF_XR     8150288    // xr: N*128 floats
// total = 14,550,288 words = 58.2 MB

#define SCAN_BLOCKS 196       // ceil(50000/256)

// ---------------------------------------------------------------------------
// In-degree histogram (real edges only). 800k int atomics, L2-resident.
__global__ void hist_cnt_kernel(const int* __restrict__ tgt, int* __restrict__ cnt)
{
    int e = blockIdx.x * 256 + threadIdx.x;
    if (e >= N_EDGES) return;
    atomicAdd(&cnt[tgt[e]], 1);
}

// ---------------------------------------------------------------------------
// CSR build over REAL edges only: row_len[n] = cnt[n]. 3-kernel exclusive scan.
__global__ void scanA_kernel(const int* __restrict__ cnt, int* __restrict__ rowptr,
                             int* __restrict__ part)
{
    __shared__ int s[256];
    int tid = threadIdx.x;
    int g = blockIdx.x * 256 + tid;
    int v = (g < N_NODES) ? cnt[g] : 0;
    s[tid] = v;
    __syncthreads();
    for (int off = 1; off < 256; off <<= 1) {
        int t = (tid >= off) ? s[tid - off] : 0;
        __syncthreads();
        s[tid] += t;
        __syncthreads();
    }
    if (g < N_NODES) rowptr[g] = s[tid] - v;        // block-local exclusive
    if (tid == 255) part[blockIdx.x] = s[255];      // block total
}

__global__ void scanB_kernel(int* __restrict__ part)
{
    __shared__ int s[256];
    int tid = threadIdx.x;
    int v = (tid < SCAN_BLOCKS) ? part[tid] : 0;    // entries >=SCAN_BLOCKS are poison
    s[tid] = v;
    __syncthreads();
    for (int off = 1; off < 256; off <<= 1) {
        int t = (tid >= off) ? s[tid - off] : 0;
        __syncthreads();
        s[tid] += t;
        __syncthreads();
    }
    part[tid] = s[tid] - v;                         // exclusive
}

__global__ void scanC_kernel(int* __restrict__ rowptr, const int* __restrict__ part,
                             int* __restrict__ cursor)
{
    int g = blockIdx.x * 256 + threadIdx.x;
    if (g >= N_NODES) return;
    int r = rowptr[g] + part[blockIdx.x];
    rowptr[g] = r;
    cursor[g] = r;
}

// Scatter real edges into CSR slots as packed (src, eid).
__global__ void scatter_kernel(const int* __restrict__ src, const int* __restrict__ tgt,
                               int* __restrict__ cursor, int2* __restrict__ csr_se)
{
    int e = blockIdx.x * 256 + threadIdx.x;
    if (e >= N_EDGES) return;
    int pos = atomicAdd(&cursor[tgt[e]], 1);
    csr_se[pos] = make_int2(src[e], e);
}

// ---------------------------------------------------------------------------
// Register-tiled GEMM: Y[M x 128] = X[M x KK] @ W[KK x 128] + b.
// (unchanged from round 8 — measured well under 148 us/launch)
template<int KK>
__global__ __launch_bounds__(256) void gemm_kernel(
    const float* __restrict__ X, const float* __restrict__ W,
    const float* __restrict__ bias, float* __restrict__ Y)
{
    __shared__ float sW[KK * 128];
    __shared__ float sX[32 * KK];
    int tid = threadIdx.x;
    // stage weights once per block (coalesced float4)
    for (int idx = tid * 4; idx < KK * 128; idx += 1024)
        *(float4*)&sW[idx] = *(const float4*)&W[idx];
    int tc = (tid & 31) * 4;          // channel group (32 groups x 4 = 128)
    int tn = (tid >> 5) * 4;          // node group    (8 groups  x 4 = 32)
    float4 b4 = *(const float4*)&bias[tc];

    for (int tb = blockIdx.x * 32; tb < N_NODES; tb += gridDim.x * 32) {
        __syncthreads();              // sW ready / prev tile's compute done
        for (int idx = tid * 4; idx < 32 * KK; idx += 1024) {
            if (tb + idx / KK < N_NODES)
                *(float4*)&sX[idx] = *(const float4*)&X[(size_t)tb * KK + idx];
        }
        __syncthreads();
        float4 a0 = b4, a1 = b4, a2 = b4, a3 = b4;
#define FMA4(A, S, Wv) A.x = fmaf(S, Wv.x, A.x); A.y = fmaf(S, Wv.y, A.y); \
                       A.z = fmaf(S, Wv.z, A.z); A.w = fmaf(S, Wv.w, A.w);
        for (int k = 0; k < KK; k += 4) {
            float4 x0 = *(const float4*)&sX[(tn + 0) * KK + k];
            float4 x1 = *(const float4*)&sX[(tn + 1) * KK + k];
            float4 x2 = *(const float4*)&sX[(tn + 2) * KK + k];
            float4 x3 = *(const float4*)&sX[(tn + 3) * KK + k];
            float4 w0 = *(const float4*)&sW[(k + 0) * 128 + tc];
            float4 w1 = *(const float4*)&sW[(k + 1) * 128 + tc];
            float4 w2 = *(const float4*)&sW[(k + 2) * 128 + tc];
            float4 w3 = *(const float4*)&sW[(k + 3) * 128 + tc];
            FMA4(a0, x0.x, w0) FMA4(a0, x0.y, w1) FMA4(a0, x0.z, w2) FMA4(a0, x0.w, w3)
            FMA4(a1, x1.x, w0) FMA4(a1, x1.y, w1) FMA4(a1, x1.z, w2) FMA4(a1, x1.w, w3)
            FMA4(a2, x2.x, w0) FMA4(a2, x2.y, w1) FMA4(a2, x2.z, w2) FMA4(a2, x2.w, w3)
            FMA4(a3, x3.x, w0) FMA4(a3, x3.y, w1) FMA4(a3, x3.z, w2) FMA4(a3, x3.w, w3)
        }
#undef FMA4
        int n0 = tb + tn;
        if (n0 + 0 < N_NODES) *(float4*)&Y[(size_t)(n0 + 0) * 128 + tc] = a0;
        if (n0 + 1 < N_NODES) *(float4*)&Y[(size_t)(n0 + 1) * 128 + tc] = a1;
        if (n0 + 2 < N_NODES) *(float4*)&Y[(size_t)(n0 + 2) * 128 + tc] = a2;
        if (n0 + 3 < N_NODES) *(float4*)&Y[(size_t)(n0 + 3) * 128 + tc] = a3;
    }
}

// ---------------------------------------------------------------------------
// FUSED logit + edge-softmax + aggregation, one wave per node, online softmax,
// 8-edge chunks for memory-level parallelism:
//  - 8 xl[src] row gathers in flight per chunk
//  - next chunk's csr entries prefetched under current compute
//  - 8 ea rows staged cooperatively (2 VMEM + 2 LDS writes per chunk)
//    into per-wave LDS, read back as broadcast ds_read_b128
//  - batched online-softmax update (1 rescale + 8 weights per chunk)
// Self-loop folded into epilogue via ee_self = (sum of real-edge ee)/cnt.
__global__ __launch_bounds__(256) void fused_kernel(
    const float* __restrict__ xl, const float* __restrict__ xr,
    const float* __restrict__ ea,
    const int2* __restrict__ csr_se, const int* __restrict__ rowptr,
    const int* __restrict__ cnt,
    const float* __restrict__ We, const float* __restrict__ att,
    const float* __restrict__ bias, float* __restrict__ out)
{
    __shared__ __align__(64) float sEa[4][8][16];   // [wave][slot][feat]
    int tid = threadIdx.x;
    int wave = tid >> 6, lane = tid & 63;
    int n = blockIdx.x * 4 + wave;
    if (n >= N_NODES) return;                       // no barriers below: safe
    int c0 = lane * 2;
    int slot = lane >> 4, feat = lane & 15;

    // per-lane We fragment: columns c0, c0+1 for all 16 edge-features
    float wreg0[16], wreg1[16];
    #pragma unroll
    for (int k = 0; k < 16; ++k) {
        float2 w2 = *(const float2*)(We + k * 128 + c0);
        wreg0[k] = w2.x; wreg1[k] = w2.y;
    }
    float a0 = att[c0], a1 = att[c0 + 1];

    int base = rowptr[n];
    int deg  = cnt[n];                              // real edges only
    float2 xrt = *(const float2*)(xr + (size_t)n * 128 + c0);
    float2 xln = *(const float2*)(xl + (size_t)n * 128 + c0);

    float m = -INFINITY, den = 0.f, acc0 = 0.f, acc1 = 0.f;
    float eesum0 = 0.f, eesum1 = 0.f;

    int2 nse0 = make_int2(0, 0), nse1 = nse0, nse2 = nse0, nse3 = nse0,
         nse4 = nse0, nse5 = nse0, nse6 = nse0, nse7 = nse0;
    if (deg > 0) {                                  // csr_se padded: +16 safe
        nse0 = csr_se[base];     nse1 = csr_se[base + 1];
        nse2 = csr_se[base + 2]; nse3 = csr_se[base + 3];
        nse4 = csr_se[base + 4]; nse5 = csr_se[base + 5];
        nse6 = csr_se[base + 6]; nse7 = csr_se[base + 7];
    }
    for (int i = 0; i < deg; i += 8) {
        int2 se0 = nse0, se1 = nse1, se2 = nse2, se3 = nse3,
             se4 = nse4, se5 = nse5, se6 = nse6, se7 = nse7;
        bool v1 = (i + 1) < deg, v2 = (i + 2) < deg, v3 = (i + 3) < deg,
             v4 = (i + 4) < deg, v5 = (i + 5) < deg, v6 = (i + 6) < deg,
             v7 = (i + 7) < deg;
        int s0 = se0.x,           e0 = se0.y;
        int s1 = v1 ? se1.x : s0, e1 = v1 ? se1.y : e0;
        int s2 = v2 ? se2.x : s0, e2 = v2 ? se2.y : e0;
        int s3 = v3 ? se3.x : s0, e3 = v3 ? se3.y : e0;
        int s4 = v4 ? se4.x : s0, e4 = v4 ? se4.y : e0;
        int s5 = v5 ? se5.x : s0, e5 = v5 ? se5.y : e0;
        int s6 = v6 ? se6.x : s0, e6 = v6 ? se6.y : e0;
        int s7 = v7 ? se7.x : s0, e7 = v7 ? se7.y : e0;

        // cooperative ea staging: lane (slot,feat) loads rows slot and slot+4
        int esA = (slot == 0) ? e0 : ((slot == 1) ? e1 : ((slot == 2) ? e2 : e3));
        int esB = (slot == 0) ? e4 : ((slot == 1) ? e5 : ((slot == 2) ? e6 : e7));
        sEa[wave][slot][feat]     = ea[(size_t)esA * 16 + feat];
        sEa[wave][slot + 4][feat] = ea[(size_t)esB * 16 + feat];

        // 8 xl row gathers in flight
        float2 x0 = *(const float2*)(xl + (size_t)s0 * 128 + c0);
        float2 x1 = *(const float2*)(xl + (size_t)s1 * 128 + c0);
        float2 x2 = *(const float2*)(xl + (size_t)s2 * 128 + c0);
        float2 x3 = *(const float2*)(xl + (size_t)s3 * 128 + c0);
        float2 x4 = *(const float2*)(xl + (size_t)s4 * 128 + c0);
        float2 x5 = *(const float2*)(xl + (size_t)s5 * 128 + c0);
        float2 x6 = *(const float2*)(xl + (size_t)s6 * 128 + c0);
        float2 x7 = *(const float2*)(xl + (size_t)s7 * 128 + c0);

        // prefetch next chunk's csr entries under this chunk's compute
        if (i + 8 < deg) {
            nse0 = csr_se[base + i + 8];  nse1 = csr_se[base + i + 9];
            nse2 = csr_se[base + i + 10]; nse3 = csr_se[base + i + 11];
            nse4 = csr_se[base + i + 12]; nse5 = csr_se[base + i + 13];
            nse6 = csr_se[base + i + 14]; nse7 = csr_se[base + i + 15];
        }

        float p0, p1, p2, p3, p4, p5, p6, p7;
#define EDGE_BODY(J, XJ, PJ, VJ)                                              \
        {                                                                     \
            const float4* er4 = (const float4*)&sEa[wave][J][0];              \
            float4 f0 = er4[0], f1 = er4[1], f2 = er4[2], f3 = er4[3];        \
            float t0 = f0.x * wreg0[0], t1 = f0.x * wreg1[0];                 \
            t0 = fmaf(f0.y, wreg0[1], t0);  t1 = fmaf(f0.y, wreg1[1], t1);    \
            t0 = fmaf(f0.z, wreg0[2], t0);  t1 = fmaf(f0.z, wreg1[2], t1);    \
            t0 = fmaf(f0.w, wreg0[3], t0);  t1 = fmaf(f0.w, wreg1[3], t1);    \
            t0 = fmaf(f1.x, wreg0[4], t0);  t1 = fmaf(f1.x, wreg1[4], t1);    \
            t0 = fmaf(f1.y, wreg0[5], t0);  t1 = fmaf(f1.y, wreg1[5], t1);    \
            t0 = fmaf(f1.z, wreg0[6], t0);  t1 = fmaf(f1.z, wreg1[6], t1);    \
            t0 = fmaf(f1.w, wreg0[7], t0);  t1 = fmaf(f1.w, wreg1[7], t1);    \
            t0 = fmaf(f2.x, wreg0[8], t0);  t1 = fmaf(f2.x, wreg1[8], t1);    \
            t0 = fmaf(f2.y, wreg0[9], t0);  t1 = fmaf(f2.y, wreg1[9], t1);    \
            t0 = fmaf(f2.z, wreg0[10], t0); t1 = fmaf(f2.z, wreg1[10], t1);   \
            t0 = fmaf(f2.w, wreg0[11], t0); t1 = fmaf(f2.w, wreg1[11], t1);   \
            t0 = fmaf(f3.x, wreg0[12], t0); t1 = fmaf(f3.x, wreg1[12], t1);   \
            t0 = fmaf(f3.y, wreg0[13], t0); t1 = fmaf(f3.y, wreg1[13], t1);   \
            t0 = fmaf(f3.z, wreg0[14], t0); t1 = fmaf(f3.z, wreg1[14], t1);   \
            t0 = fmaf(f3.w, wreg0[15], t0); t1 = fmaf(f3.w, wreg1[15], t1);   \
            eesum0 += (VJ) ? t0 : 0.f;      eesum1 += (VJ) ? t1 : 0.f;        \
            float q0 = XJ.x + xrt.x + t0;   q0 = (q0 > 0.f) ? q0 : NEG * q0;  \
            float q1 = XJ.y + xrt.y + t1;   q1 = (q1 > 0.f) ? q1 : NEG * q1;  \
            PJ = fmaf(q0, a0, q1 * a1);                                       \
        }
        EDGE_BODY(0, x0, p0, true)
        EDGE_BODY(1, x1, p1, v1)
        EDGE_BODY(2, x2, p2, v2)
        EDGE_BODY(3, x3, p3, v3)
        EDGE_BODY(4, x4, p4, v4)
        EDGE_BODY(5, x5, p5, v5)
        EDGE_BODY(6, x6, p6, v6)
        EDGE_BODY(7, x7, p7, v7)
#undef EDGE_BODY

        // head-group (16-lane) logit reduces, 8 independent chains
        #pragma unroll
        for (int msk = 1; msk < 16; msk <<= 1) {
            p0 += __shfl_xor(p0, msk);
            p1 += __shfl_xor(p1, msk);
            p2 += __shfl_xor(p2, msk);
            p3 += __shfl_xor(p3, msk);
            p4 += __shfl_xor(p4, msk);
            p5 += __shfl_xor(p5, msk);
            p6 += __shfl_xor(p6, msk);
            p7 += __shfl_xor(p7, msk);
        }
        p1 = v1 ? p1 : -INFINITY;
        p2 = v2 ? p2 : -INFINITY;
        p3 = v3 ? p3 : -INFINITY;
        p4 = v4 ? p4 : -INFINITY;
        p5 = v5 ? p5 : -INFINITY;
        p6 = v6 ? p6 : -INFINITY;
        p7 = v7 ? p7 : -INFINITY;

        // batched online-softmax update
        float nmA = fmaxf(fmaxf(p0, p1), fmaxf(p2, p3));
        float nmB = fmaxf(fmaxf(p4, p5), fmaxf(p6, p7));
        float nm  = fmaxf(m, fmaxf(nmA, nmB));
        float sc = __expf(m - nm);
        float w0 = __expf(p0 - nm), w1 = __expf(p1 - nm);
        float w2 = __expf(p2 - nm), w3 = __expf(p3 - nm);
        float w4 = __expf(p4 - nm), w5 = __expf(p5 - nm);
        float w6 = __expf(p6 - nm), w7 = __expf(p7 - nm);
        den  = fmaf(den, sc, ((w0 + w1) + (w2 + w3)) + ((w4 + w5) + (w6 + w7)));
        float s0x = fmaf(w0, x0.x, fmaf(w1, x1.x, fmaf(w2, x2.x, w3 * x3.x)));
        float s1x = fmaf(w4, x4.x, fmaf(w5, x5.x, fmaf(w6, x6.x, w7 * x7.x)));
        float s0y = fmaf(w0, x0.y, fmaf(w1, x1.y, fmaf(w2, x2.y, w3 * x3.y)));
        float s1y = fmaf(w4, x4.y, fmaf(w5, x5.y, fmaf(w6, x6.y, w7 * x7.y)));
        acc0 = fmaf(acc0, sc, s0x + s1x);
        acc1 = fmaf(acc1, sc, s0y + s1y);
        m = nm;
    }

    // self-loop with mean edge_attr: ee_self = eesum / max(cnt,1)
    {
        float rc = 1.0f / (float)(deg > 0 ? deg : 1);
        float ee0 = eesum0 * rc, ee1 = eesum1 * rc;
        float q0 = xln.x + xrt.x + ee0; q0 = (q0 > 0.f) ? q0 : NEG * q0;
        float q1 = xln.y + xrt.y + ee1; q1 = (q1 > 0.f) ? q1 : NEG * q1;
        float part = fmaf(q0, a0, q1 * a1);
        part += __shfl_xor(part, 1);
        part += __shfl_xor(part, 2);
        part += __shfl_xor(part, 4);
        part += __shfl_xor(part, 8);
        float nm = fmaxf(m, part);
        float sc = __expf(m - nm);
        float w  = __expf(part - nm);
        den  = fmaf(den, sc, w);
        acc0 = fmaf(acc0, sc, w * xln.x);
        acc1 = fmaf(acc1, sc, w * xln.y);
    }
    float rd = 1.0f / den;
    float o0 = fmaxf(fmaf(acc0, rd, bias[c0]), 0.f);     // + bias, ReLU
    float o1 = fmaxf(fmaf(acc1, rd, bias[c0 + 1]), 0.f);
    *(float2*)(out + (size_t)n * 128 + c0) = make_float2(o0, o1);
}

// ---------------------------------------------------------------------------
extern "C" void kernel_launch(void* const* d_in, const int* in_sizes, int n_in,
                              void* d_out, int out_size, void* d_ws, size_t ws_size,
                              hipStream_t stream)
{
    const float* x    = (const float*)d_in[0];
    const int*   ei   = (const int*)d_in[1];
    const float* ea   = (const float*)d_in[2];
    const float* w1l  = (const float*)d_in[3];
    const float* b1l  = (const float*)d_in[4];
    const float* w1r  = (const float*)d_in[5];
    const float* b1r  = (const float*)d_in[6];
    const float* w1e  = (const float*)d_in[7];
    const float* att1 = (const float*)d_in[8];
    const float* bias1= (const float*)d_in[9];
    const float* w2l  = (const float*)d_in[10];
    const float* b2l  = (const float*)d_in[11];
    const float* w2r  = (const float*)d_in[12];
    const float* b2r  = (const float*)d_in[13];
    const float* w2e  = (const float*)d_in[14];
    const float* att2 = (const float*)d_in[15];
    const float* bias2= (const float*)d_in[16];
    const float* hw   = (const float*)d_in[17];
    const float* hb   = (const float*)d_in[18];
    const int* src = ei;
    const int* tgt = ei + N_EDGES;

    float* ws     = (float*)d_ws;
    int*   cnt    = (int*)(ws + OFF_CNT);
    int*   rowptr = (int*)(ws + OFF_ROWPTR);
    int*   cursor = (int*)(ws + OFF_CURSOR);
    int*   part   = (int*)(ws + OFF_PART);
    int2*  csr_se = (int2*)(ws + OFF_CSRSE);
    float* xl     = ws + OFF_XL;
    float* xr     = ws + OFF_XR;
    float* out    = (float*)d_out;

    // zero cnt only (ws is poisoned 0xAA each call); everything else is
    // fully overwritten before being read.
    hipMemsetAsync(cnt, 0, (size_t)N_NODES * 4, stream);

    hist_cnt_kernel<<<(N_EDGES + 255) / 256, 256, 0, stream>>>(tgt, cnt);
    scanA_kernel<<<SCAN_BLOCKS, 256, 0, stream>>>(cnt, rowptr, part);
    scanB_kernel<<<1, 256, 0, stream>>>(part);
    scanC_kernel<<<SCAN_BLOCKS, 256, 0, stream>>>(rowptr, part, cursor);
    scatter_kernel<<<(N_EDGES + 255) / 256, 256, 0, stream>>>(src, tgt, cursor, csr_se);

    // conv1 (Fin = 64): xl = x@w1l+b1l, xr = x@w1r+b1r
    gemm_kernel<64><<<1024, 256, 0, stream>>>(x, w1l, b1l, xl);
    gemm_kernel<64><<<1024, 256, 0, stream>>>(x, w1r, b1r, xr);
    fused_kernel<<<(N_NODES + 3) / 4, 256, 0, stream>>>(
        xl, xr, ea, csr_se, rowptr, cnt, w1e, att1, bias1, out);

    // conv2 (Fin = 128, input = h1 in d_out)
    gemm_kernel<128><<<1024, 256, 0, stream>>>(out, w2l, b2l, xl);
    gemm_kernel<128><<<1024, 256, 0, stream>>>(out, w2r, b2r, xr);
    fused_kernel<<<(N_NODES + 3) / 4, 256, 0, stream>>>(
        xl, xr, ea, csr_se, rowptr, cnt, w2e, att2, bias2, out);

    // history head, in place on d_out (row-disjoint tiles => safe)
    gemm_kernel<128><<<1024, 256, 0, stream>>>(out, hw, hb, out);
}

// Round 13
// 591.160 us; speedup vs baseline: 1.0808x; 1.0808x over previous
//
#include <hip/hip_runtime.h>
#include <hip/hip_bf16.h>
#include <math.h>

// Problem constants (from reference)
#define N_NODES 50000
#define N_EDGES 800000
#define NEG     0.2f

// Workspace layout (in 4-byte words)
#define OFF_CNT    0          // cnt: N ints (in-degree, real edges only)
#define OFF_ROWPTR 50000      // row_ptr: N ints
#define OFF_CURSOR 100000     // cursor: N ints
#define OFF_PART   150000     // scan partials: 256 ints
#define OFF_CSRSE  150256     // csr_se: E int2 + 16 int2 pad = 1,600,032 words
#define OFF_XL     1750288    // xl: N*128 floats
#define OFF_XR     8150288    // xr: N*128 floats
// total = 14,550,288 words = 58.2 MB

#define SCAN_BLOCKS 196       // ceil(50000/256)

// ---------------------------------------------------------------------------
// In-degree histogram (real edges only). 800k int atomics, L2-resident.
__global__ void hist_cnt_kernel(const int* __restrict__ tgt, int* __restrict__ cnt)
{
    int e = blockIdx.x * 256 + threadIdx.x;
    if (e >= N_EDGES) return;
    atomicAdd(&cnt[tgt[e]], 1);
}

// ---------------------------------------------------------------------------
// CSR build over REAL edges only: row_len[n] = cnt[n]. 3-kernel exclusive scan.
__global__ void scanA_kernel(const int* __restrict__ cnt, int* __restrict__ rowptr,
                             int* __restrict__ part)
{
    __shared__ int s[256];
    int tid = threadIdx.x;
    int g = blockIdx.x * 256 + tid;
    int v = (g < N_NODES) ? cnt[g] : 0;
    s[tid] = v;
    __syncthreads();
    for (int off = 1; off < 256; off <<= 1) {
        int t = (tid >= off) ? s[tid - off] : 0;
        __syncthreads();
        s[tid] += t;
        __syncthreads();
    }
    if (g < N_NODES) rowptr[g] = s[tid] - v;        // block-local exclusive
    if (tid == 255) part[blockIdx.x] = s[255];      // block total
}

__global__ void scanB_kernel(int* __restrict__ part)
{
    __shared__ int s[256];
    int tid = threadIdx.x;
    int v = (tid < SCAN_BLOCKS) ? part[tid] : 0;    // entries >=SCAN_BLOCKS are poison
    s[tid] = v;
    __syncthreads();
    for (int off = 1; off < 256; off <<= 1) {
        int t = (tid >= off) ? s[tid - off] : 0;
        __syncthreads();
        s[tid] += t;
        __syncthreads();
    }
    part[tid] = s[tid] - v;                         // exclusive
}

__global__ void scanC_kernel(int* __restrict__ rowptr, const int* __restrict__ part,
                             int* __restrict__ cursor)
{
    int g = blockIdx.x * 256 + threadIdx.x;
    if (g >= N_NODES) return;
    int r = rowptr[g] + part[blockIdx.x];
    rowptr[g] = r;
    cursor[g] = r;
}

// Scatter real edges into CSR slots as packed (src, eid).
__global__ void scatter_kernel(const int* __restrict__ src, const int* __restrict__ tgt,
                               int* __restrict__ cursor, int2* __restrict__ csr_se)
{
    int e = blockIdx.x * 256 + threadIdx.x;
    if (e >= N_EDGES) return;
    int pos = atomicAdd(&cursor[tgt[e]], 1);
    csr_se[pos] = make_int2(src[e], e);
}

// ---------------------------------------------------------------------------
// Merged L/R GEMM, conv1 (KK=64): xl = X@Wl+bl and xr = X@Wr+br in one pass.
// Both weight mats in LDS (2x32KB) + X tile (8KB) = 72KB -> 2 blocks/CU.
// X staged ONCE per tile, used for both outputs (2x compute per barrier).
// Thread = 4 nodes x 4 channels x {L,R} = 32 accumulators.
__global__ __launch_bounds__(256) void gemm_lr64_kernel(
    const float* __restrict__ X,
    const float* __restrict__ Wl, const float* __restrict__ bl,
    const float* __restrict__ Wr, const float* __restrict__ br,
    float* __restrict__ xl, float* __restrict__ xr)
{
    __shared__ float sWl[64 * 128];
    __shared__ float sWr[64 * 128];
    __shared__ float sX[32 * 64];
    int tid = threadIdx.x;
    for (int idx = tid * 4; idx < 64 * 128; idx += 1024) {
        *(float4*)&sWl[idx] = *(const float4*)&Wl[idx];
        *(float4*)&sWr[idx] = *(const float4*)&Wr[idx];
    }
    int tc = (tid & 31) * 4;
    int tn = (tid >> 5) * 4;
    float4 bl4 = *(const float4*)&bl[tc];
    float4 br4 = *(const float4*)&br[tc];

    for (int tb = blockIdx.x * 32; tb < N_NODES; tb += gridDim.x * 32) {
        __syncthreads();
        for (int idx = tid * 4; idx < 32 * 64; idx += 1024) {
            if (tb + idx / 64 < N_NODES)
                *(float4*)&sX[idx] = *(const float4*)&X[(size_t)tb * 64 + idx];
        }
        __syncthreads();
        float4 a0 = bl4, a1 = bl4, a2 = bl4, a3 = bl4;
        float4 c0 = br4, c1 = br4, c2 = br4, c3 = br4;
#define FMA4(A, S, Wv) A.x = fmaf(S, Wv.x, A.x); A.y = fmaf(S, Wv.y, A.y); \
                       A.z = fmaf(S, Wv.z, A.z); A.w = fmaf(S, Wv.w, A.w);
        for (int k = 0; k < 64; k += 4) {
            float4 x0 = *(const float4*)&sX[(tn + 0) * 64 + k];
            float4 x1 = *(const float4*)&sX[(tn + 1) * 64 + k];
            float4 x2 = *(const float4*)&sX[(tn + 2) * 64 + k];
            float4 x3 = *(const float4*)&sX[(tn + 3) * 64 + k];
            #pragma unroll
            for (int kk = 0; kk < 4; ++kk) {
                float4 wl = *(const float4*)&sWl[(k + kk) * 128 + tc];
                float4 wr = *(const float4*)&sWr[(k + kk) * 128 + tc];
                float xs0 = (kk == 0) ? x0.x : (kk == 1) ? x0.y : (kk == 2) ? x0.z : x0.w;
                float xs1 = (kk == 0) ? x1.x : (kk == 1) ? x1.y : (kk == 2) ? x1.z : x1.w;
                float xs2 = (kk == 0) ? x2.x : (kk == 1) ? x2.y : (kk == 2) ? x2.z : x2.w;
                float xs3 = (kk == 0) ? x3.x : (kk == 1) ? x3.y : (kk == 2) ? x3.z : x3.w;
                FMA4(a0, xs0, wl) FMA4(a1, xs1, wl) FMA4(a2, xs2, wl) FMA4(a3, xs3, wl)
                FMA4(c0, xs0, wr) FMA4(c1, xs1, wr) FMA4(c2, xs2, wr) FMA4(c3, xs3, wr)
            }
        }
#undef FMA4
        int n0 = tb + tn;
        if (n0 + 0 < N_NODES) { *(float4*)&xl[(size_t)(n0 + 0) * 128 + tc] = a0;
                                *(float4*)&xr[(size_t)(n0 + 0) * 128 + tc] = c0; }
        if (n0 + 1 < N_NODES) { *(float4*)&xl[(size_t)(n0 + 1) * 128 + tc] = a1;
                                *(float4*)&xr[(size_t)(n0 + 1) * 128 + tc] = c1; }
        if (n0 + 2 < N_NODES) { *(float4*)&xl[(size_t)(n0 + 2) * 128 + tc] = a2;
                                *(float4*)&xr[(size_t)(n0 + 2) * 128 + tc] = c2; }
        if (n0 + 3 < N_NODES) { *(float4*)&xl[(size_t)(n0 + 3) * 128 + tc] = a3;
                                *(float4*)&xr[(size_t)(n0 + 3) * 128 + tc] = c3; }
    }
}

// ---------------------------------------------------------------------------
// Merged L/R GEMM, conv2 (KK=128), channel-split: each block computes 64 of
// the 128 output channels for BOTH L and R. LDS = 32+32+16 = 80KB (2 blk/CU).
// Grid = 2048: even/odd blocks take channel half 0/1; X tile staged once.
// Thread = 4 nodes x 2 channels x {L,R} = 16 accumulators.
__global__ __launch_bounds__(256) void gemm_lr128_kernel(
    const float* __restrict__ X,
    const float* __restrict__ Wl, const float* __restrict__ bl,
    const float* __restrict__ Wr, const float* __restrict__ br,
    float* __restrict__ xl, float* __restrict__ xr)
{
    __shared__ float sWl[128 * 64];
    __shared__ float sWr[128 * 64];
    __shared__ float sX[32 * 128];
    int tid = threadIdx.x;
    int half = blockIdx.x & 1;
    int cbase = half * 64;
    int bslot = blockIdx.x >> 1;
    int nslots = gridDim.x >> 1;
    for (int idx = tid * 4; idx < 128 * 64; idx += 1024) {
        int k = idx >> 6, c = idx & 63;
        *(float4*)&sWl[idx] = *(const float4*)&Wl[k * 128 + cbase + c];
        *(float4*)&sWr[idx] = *(const float4*)&Wr[k * 128 + cbase + c];
    }
    int tc = (tid & 31) * 2;
    int tn = (tid >> 5) * 4;
    float2 bl2 = *(const float2*)&bl[cbase + tc];
    float2 br2 = *(const float2*)&br[cbase + tc];

    for (int tb = bslot * 32; tb < N_NODES; tb += nslots * 32) {
        __syncthreads();
        for (int idx = tid * 4; idx < 32 * 128; idx += 1024) {
            if (tb + (idx >> 7) < N_NODES)
                *(float4*)&sX[idx] = *(const float4*)&X[(size_t)tb * 128 + idx];
        }
        __syncthreads();
        float2 a0 = bl2, a1 = bl2, a2 = bl2, a3 = bl2;
        float2 c0 = br2, c1 = br2, c2 = br2, c3 = br2;
#define FMA2(A, S, Wv) A.x = fmaf(S, Wv.x, A.x); A.y = fmaf(S, Wv.y, A.y);
        for (int k = 0; k < 128; k += 4) {
            float4 x0 = *(const float4*)&sX[(tn + 0) * 128 + k];
            float4 x1 = *(const float4*)&sX[(tn + 1) * 128 + k];
            float4 x2 = *(const float4*)&sX[(tn + 2) * 128 + k];
            float4 x3 = *(const float4*)&sX[(tn + 3) * 128 + k];
            #pragma unroll
            for (int kk = 0; kk < 4; ++kk) {
                float2 wl = *(const float2*)&sWl[(k + kk) * 64 + tc];
                float2 wr = *(const float2*)&sWr[(k + kk) * 64 + tc];
                float xs0 = (kk == 0) ? x0.x : (kk == 1) ? x0.y : (kk == 2) ? x0.z : x0.w;
                float xs1 = (kk == 0) ? x1.x : (kk == 1) ? x1.y : (kk == 2) ? x1.z : x1.w;
                float xs2 = (kk == 0) ? x2.x : (kk == 1) ? x2.y : (kk == 2) ? x2.z : x2.w;
                float xs3 = (kk == 0) ? x3.x : (kk == 1) ? x3.y : (kk == 2) ? x3.z : x3.w;
                FMA2(a0, xs0, wl) FMA2(a1, xs1, wl) FMA2(a2, xs2, wl) FMA2(a3, xs3, wl)
                FMA2(c0, xs0, wr) FMA2(c1, xs1, wr) FMA2(c2, xs2, wr) FMA2(c3, xs3, wr)
            }
        }
#undef FMA2
        int n0 = tb + tn;
        if (n0 + 0 < N_NODES) { *(float2*)&xl[(size_t)(n0 + 0) * 128 + cbase + tc] = a0;
                                *(float2*)&xr[(size_t)(n0 + 0) * 128 + cbase + tc] = c0; }
        if (n0 + 1 < N_NODES) { *(float2*)&xl[(size_t)(n0 + 1) * 128 + cbase + tc] = a1;
                                *(float2*)&xr[(size_t)(n0 + 1) * 128 + cbase + tc] = c1; }
        if (n0 + 2 < N_NODES) { *(float2*)&xl[(size_t)(n0 + 2) * 128 + cbase + tc] = a2;
                                *(float2*)&xr[(size_t)(n0 + 2) * 128 + cbase + tc] = c2; }
        if (n0 + 3 < N_NODES) { *(float2*)&xl[(size_t)(n0 + 3) * 128 + cbase + tc] = a3;
                                *(float2*)&xr[(size_t)(n0 + 3) * 128 + cbase + tc] = c3; }
    }
}

// ---------------------------------------------------------------------------
// Register-tiled GEMM (single output) for the history head.
template<int KK>
__global__ __launch_bounds__(256) void gemm_kernel(
    const float* __restrict__ X, const float* __restrict__ W,
    const float* __restrict__ bias, float* __restrict__ Y)
{
    __shared__ float sW[KK * 128];
    __shared__ float sX[32 * KK];
    int tid = threadIdx.x;
    for (int idx = tid * 4; idx < KK * 128; idx += 1024)
        *(float4*)&sW[idx] = *(const float4*)&W[idx];
    int tc = (tid & 31) * 4;
    int tn = (tid >> 5) * 4;
    float4 b4 = *(const float4*)&bias[tc];

    for (int tb = blockIdx.x * 32; tb < N_NODES; tb += gridDim.x * 32) {
        __syncthreads();
        for (int idx = tid * 4; idx < 32 * KK; idx += 1024) {
            if (tb + idx / KK < N_NODES)
                *(float4*)&sX[idx] = *(const float4*)&X[(size_t)tb * KK + idx];
        }
        __syncthreads();
        float4 a0 = b4, a1 = b4, a2 = b4, a3 = b4;
#define FMA4(A, S, Wv) A.x = fmaf(S, Wv.x, A.x); A.y = fmaf(S, Wv.y, A.y); \
                       A.z = fmaf(S, Wv.z, A.z); A.w = fmaf(S, Wv.w, A.w);
        for (int k = 0; k < KK; k += 4) {
            float4 x0 = *(const float4*)&sX[(tn + 0) * KK + k];
            float4 x1 = *(const float4*)&sX[(tn + 1) * KK + k];
            float4 x2 = *(const float4*)&sX[(tn + 2) * KK + k];
            float4 x3 = *(const float4*)&sX[(tn + 3) * KK + k];
            float4 w0 = *(const float4*)&sW[(k + 0) * 128 + tc];
            float4 w1 = *(const float4*)&sW[(k + 1) * 128 + tc];
            float4 w2 = *(const float4*)&sW[(k + 2) * 128 + tc];
            float4 w3 = *(const float4*)&sW[(k + 3) * 128 + tc];
            FMA4(a0, x0.x, w0) FMA4(a0, x0.y, w1) FMA4(a0, x0.z, w2) FMA4(a0, x0.w, w3)
            FMA4(a1, x1.x, w0) FMA4(a1, x1.y, w1) FMA4(a1, x1.z, w2) FMA4(a1, x1.w, w3)
            FMA4(a2, x2.x, w0) FMA4(a2, x2.y, w1) FMA4(a2, x2.z, w2) FMA4(a2, x2.w, w3)
            FMA4(a3, x3.x, w0) FMA4(a3, x3.y, w1) FMA4(a3, x3.z, w2) FMA4(a3, x3.w, w3)
        }
#undef FMA4
        int n0 = tb + tn;
        if (n0 + 0 < N_NODES) *(float4*)&Y[(size_t)(n0 + 0) * 128 + tc] = a0;
        if (n0 + 1 < N_NODES) *(float4*)&Y[(size_t)(n0 + 1) * 128 + tc] = a1;
        if (n0 + 2 < N_NODES) *(float4*)&Y[(size_t)(n0 + 2) * 128 + tc] = a2;
        if (n0 + 3 < N_NODES) *(float4*)&Y[(size_t)(n0 + 3) * 128 + tc] = a3;
    }
}

// ---------------------------------------------------------------------------
// FUSED logit + edge-softmax + aggregation, one wave per node, online softmax,
// 4-edge chunks (measured optimum: chunk=8 regressed via VGPR/occupancy).
__global__ __launch_bounds__(256) void fused_kernel(
    const float* __restrict__ xl, const float* __restrict__ xr,
    const float* __restrict__ ea,
    const int2* __restrict__ csr_se, const int* __restrict__ rowptr,
    const int* __restrict__ cnt,
    const float* __restrict__ We, const float* __restrict__ att,
    const float* __restrict__ bias, float* __restrict__ out)
{
    __shared__ __align__(64) float sEa[4][4][16];   // [wave][slot][feat]
    int tid = threadIdx.x;
    int wave = tid >> 6, lane = tid & 63;
    int n = blockIdx.x * 4 + wave;
    if (n >= N_NODES) return;                       // no barriers below: safe
    int c0 = lane * 2;
    int slot = lane >> 4, feat = lane & 15;

    // per-lane We fragment: columns c0, c0+1 for all 16 edge-features
    float wreg0[16], wreg1[16];
    #pragma unroll
    for (int k = 0; k < 16; ++k) {
        float2 w2 = *(const float2*)(We + k * 128 + c0);
        wreg0[k] = w2.x; wreg1[k] = w2.y;
    }
    float a0 = att[c0], a1 = att[c0 + 1];

    int base = rowptr[n];
    int deg  = cnt[n];                              // real edges only
    float2 xrt = *(const float2*)(xr + (size_t)n * 128 + c0);
    float2 xln = *(const float2*)(xl + (size_t)n * 128 + c0);

    float m = -INFINITY, den = 0.f, acc0 = 0.f, acc1 = 0.f;
    float eesum0 = 0.f, eesum1 = 0.f;

    int2 nse0 = make_int2(0, 0), nse1 = nse0, nse2 = nse0, nse3 = nse0;
    if (deg > 0) {                                  // csr_se padded: +16 safe
        nse0 = csr_se[base];     nse1 = csr_se[base + 1];
        nse2 = csr_se[base + 2]; nse3 = csr_se[base + 3];
    }
    for (int i = 0; i < deg; i += 4) {
        int2 se0 = nse0, se1 = nse1, se2 = nse2, se3 = nse3;
        bool v1 = (i + 1) < deg, v2 = (i + 2) < deg, v3 = (i + 3) < deg;
        int s0 = se0.x,           e0 = se0.y;
        int s1 = v1 ? se1.x : s0, e1 = v1 ? se1.y : e0;
        int s2 = v2 ? se2.x : s0, e2 = v2 ? se2.y : e0;
        int s3 = v3 ? se3.x : s0, e3 = v3 ? se3.y : e0;

        // cooperative ea staging: lane (slot,feat) loads ea[e_slot][feat]
        int es = (slot == 0) ? e0 : ((slot == 1) ? e1 : ((slot == 2) ? e2 : e3));
        sEa[wave][slot][feat] = ea[(size_t)es * 16 + feat];

        // 4 xl row gathers in flight
        float2 x0 = *(const float2*)(xl + (size_t)s0 * 128 + c0);
        float2 x1 = *(const float2*)(xl + (size_t)s1 * 128 + c0);
        float2 x2 = *(const float2*)(xl + (size_t)s2 * 128 + c0);
        float2 x3 = *(const float2*)(xl + (size_t)s3 * 128 + c0);

        // prefetch next chunk's csr entries under this chunk's compute
        if (i + 4 < deg) {
            nse0 = csr_se[base + i + 4]; nse1 = csr_se[base + i + 5];
            nse2 = csr_se[base + i + 6]; nse3 = csr_se[base + i + 7];
        }

        float p0, p1, p2, p3;
#define EDGE_BODY(J, XJ, PJ, VJ)                                              \
        {                                                                     \
            const float4* er4 = (const float4*)&sEa[wave][J][0];              \
            float4 f0 = er4[0], f1 = er4[1], f2 = er4[2], f3 = er4[3];        \
            float t0 = f0.x * wreg0[0], t1 = f0.x * wreg1[0];                 \
            t0 = fmaf(f0.y, wreg0[1], t0);  t1 = fmaf(f0.y, wreg1[1], t1);    \
            t0 = fmaf(f0.z, wreg0[2], t0);  t1 = fmaf(f0.z, wreg1[2], t1);    \
            t0 = fmaf(f0.w, wreg0[3], t0);  t1 = fmaf(f0.w, wreg1[3], t1);    \
            t0 = fmaf(f1.x, wreg0[4], t0);  t1 = fmaf(f1.x, wreg1[4], t1);    \
            t0 = fmaf(f1.y, wreg0[5], t0);  t1 = fmaf(f1.y, wreg1[5], t1);    \
            t0 = fmaf(f1.z, wreg0[6], t0);  t1 = fmaf(f1.z, wreg1[6], t1);    \
            t0 = fmaf(f1.w, wreg0[7], t0);  t1 = fmaf(f1.w, wreg1[7], t1);    \
            t0 = fmaf(f2.x, wreg0[8], t0);  t1 = fmaf(f2.x, wreg1[8], t1);    \
            t0 = fmaf(f2.y, wreg0[9], t0);  t1 = fmaf(f2.y, wreg1[9], t1);    \
            t0 = fmaf(f2.z, wreg0[10], t0); t1 = fmaf(f2.z, wreg1[10], t1);   \
            t0 = fmaf(f2.w, wreg0[11], t0); t1 = fmaf(f2.w, wreg1[11], t1);   \
            t0 = fmaf(f3.x, wreg0[12], t0); t1 = fmaf(f3.x, wreg1[12], t1);   \
            t0 = fmaf(f3.y, wreg0[13], t0); t1 = fmaf(f3.y, wreg1[13], t1);   \
            t0 = fmaf(f3.z, wreg0[14], t0); t1 = fmaf(f3.z, wreg1[14], t1);   \
            t0 = fmaf(f3.w, wreg0[15], t0); t1 = fmaf(f3.w, wreg1[15], t1);   \
            eesum0 += (VJ) ? t0 : 0.f;      eesum1 += (VJ) ? t1 : 0.f;        \
            float q0 = XJ.x + xrt.x + t0;   q0 = (q0 > 0.f) ? q0 : NEG * q0;  \
            float q1 = XJ.y + xrt.y + t1;   q1 = (q1 > 0.f) ? q1 : NEG * q1;  \
            PJ = fmaf(q0, a0, q1 * a1);                                       \
        }
        EDGE_BODY(0, x0, p0, true)
        EDGE_BODY(1, x1, p1, v1)
        EDGE_BODY(2, x2, p2, v2)
        EDGE_BODY(3, x3, p3, v3)
#undef EDGE_BODY

        // head-group (16-lane) logit reduces, 4 independent chains
        #pragma unroll
        for (int msk = 1; msk < 16; msk <<= 1) {
            p0 += __shfl_xor(p0, msk);
            p1 += __shfl_xor(p1, msk);
            p2 += __shfl_xor(p2, msk);
            p3 += __shfl_xor(p3, msk);
        }
        p1 = v1 ? p1 : -INFINITY;
        p2 = v2 ? p2 : -INFINITY;
        p3 = v3 ? p3 : -INFINITY;

        // batched online-softmax update
        float nm = fmaxf(fmaxf(m, p0), fmaxf(fmaxf(p1, p2), p3));
        float sc = __expf(m - nm);
        float w0 = __expf(p0 - nm), w1 = __expf(p1 - nm);
        float w2 = __expf(p2 - nm), w3 = __expf(p3 - nm);
        den  = fmaf(den, sc, (w0 + w1) + (w2 + w3));
        acc0 = fmaf(acc0, sc, fmaf(w0, x0.x, fmaf(w1, x1.x, fmaf(w2, x2.x, w3 * x3.x))));
        acc1 = fmaf(acc1, sc, fmaf(w0, x0.y, fmaf(w1, x1.y, fmaf(w2, x2.y, w3 * x3.y))));
        m = nm;
    }

    // self-loop with mean edge_attr: ee_self = eesum / max(cnt,1)
    {
        float rc = 1.0f / (float)(deg > 0 ? deg : 1);
        float ee0 = eesum0 * rc, ee1 = eesum1 * rc;
        float q0 = xln.x + xrt.x + ee0; q0 = (q0 > 0.f) ? q0 : NEG * q0;
        float q1 = xln.y + xrt.y + ee1; q1 = (q1 > 0.f) ? q1 : NEG * q1;
        float part = fmaf(q0, a0, q1 * a1);
        part += __shfl_xor(part, 1);
        part += __shfl_xor(part, 2);
        part += __shfl_xor(part, 4);
        part += __shfl_xor(part, 8);
        float nm = fmaxf(m, part);
        float sc = __expf(m - nm);
        float w  = __expf(part - nm);
        den  = fmaf(den, sc, w);
        acc0 = fmaf(acc0, sc, w * xln.x);
        acc1 = fmaf(acc1, sc, w * xln.y);
    }
    float rd = 1.0f / den;
    float o0 = fmaxf(fmaf(acc0, rd, bias[c0]), 0.f);     // + bias, ReLU
    float o1 = fmaxf(fmaf(acc1, rd, bias[c0 + 1]), 0.f);
    *(float2*)(out + (size_t)n * 128 + c0) = make_float2(o0, o1);
}

// ---------------------------------------------------------------------------
extern "C" void kernel_launch(void* const* d_in, const int* in_sizes, int n_in,
                              void* d_out, int out_size, void* d_ws, size_t ws_size,
                              hipStream_t stream)
{
    const float* x    = (const float*)d_in[0];
    const int*   ei   = (const int*)d_in[1];
    const float* ea   = (const float*)d_in[2];
    const float* w1l  = (const float*)d_in[3];
    const float* b1l  = (const float*)d_in[4];
    const float* w1r  = (const float*)d_in[5];
    const float* b1r  = (const float*)d_in[6];
    const float* w1e  = (const float*)d_in[7];
    const float* att1 = (const float*)d_in[8];
    const float* bias1= (const float*)d_in[9];
    const float* w2l  = (const float*)d_in[10];
    const float* b2l  = (const float*)d_in[11];
    const float* w2r  = (const float*)d_in[12];
    const float* b2r  = (const float*)d_in[13];
    const float* w2e  = (const float*)d_in[14];
    const float* att2 = (const float*)d_in[15];
    const float* bias2= (const float*)d_in[16];
    const float* hw   = (const float*)d_in[17];
    const float* hb   = (const float*)d_in[18];
    const int* src = ei;
    const int* tgt = ei + N_EDGES;

    float* ws     = (float*)d_ws;
    int*   cnt    = (int*)(ws + OFF_CNT);
    int*   rowptr = (int*)(ws + OFF_ROWPTR);
    int*   cursor = (int*)(ws + OFF_CURSOR);
    int*   part   = (int*)(ws + OFF_PART);
    int2*  csr_se = (int2*)(ws + OFF_CSRSE);
    float* xl     = ws + OFF_XL;
    float* xr     = ws + OFF_XR;
    float* out    = (float*)d_out;

    // zero cnt only (ws is poisoned 0xAA each call); everything else is
    // fully overwritten before being read.
    hipMemsetAsync(cnt, 0, (size_t)N_NODES * 4, stream);

    hist_cnt_kernel<<<(N_EDGES + 255) / 256, 256, 0, stream>>>(tgt, cnt);
    scanA_kernel<<<SCAN_BLOCKS, 256, 0, stream>>>(cnt, rowptr, part);
    scanB_kernel<<<1, 256, 0, stream>>>(part);
    scanC_kernel<<<SCAN_BLOCKS, 256, 0, stream>>>(rowptr, part, cursor);
    scatter_kernel<<<(N_EDGES + 255) / 256, 256, 0, stream>>>(src, tgt, cursor, csr_se);

    // conv1 (Fin = 64): xl = x@w1l+b1l AND xr = x@w1r+b1r in one launch
    gemm_lr64_kernel<<<1024, 256, 0, stream>>>(x, w1l, b1l, w1r, b1r, xl, xr);
    fused_kernel<<<(N_NODES + 3) / 4, 256, 0, stream>>>(
        xl, xr, ea, csr_se, rowptr, cnt, w1e, att1, bias1, out);

    // conv2 (Fin = 128, input = h1 in d_out): merged L/R, channel-split
    gemm_lr128_kernel<<<2048, 256, 0, stream>>>(out, w2l, b2l, w2r, b2r, xl, xr);
    fused_kernel<<<(N_NODES + 3) / 4, 256, 0, stream>>>(
        xl, xr, ea, csr_se, rowptr, cnt, w2e, att2, bias2, out);

    // history head, in place on d_out (row-disjoint tiles => safe)
    gemm_kernel<128><<<1024, 256, 0, stream>>>(out, hw, hb, out);
}